// Round 3
// baseline (482.383 us; speedup 1.0000x reference)
//
#include <hip/hip_runtime.h>
#include <cstdint>

// ---------------------------------------------------------------------------
// Qwen2 attention block, MI355X/gfx950. Round 2: attention rework v3 —
// swapped QK^T (lane-local softmax rows), base-2 softmax w/ pre-scaled Q,
// defer-max rescale, full/tail loop split, cvt_pk P-pack, 1024-block grid.
// ---------------------------------------------------------------------------

typedef short bf16x8 __attribute__((ext_vector_type(8)));
typedef float f32x4 __attribute__((ext_vector_type(4)));

static constexpr int Bsz = 2, Ssz = 2048, Hsz = 2048;
static constexpr int NH = 16, NKV = 4, HD = 128;
static constexpr int Mrows = Bsz * Ssz;              // 4096
static constexpr int NQKV = (NH + 2 * NKV) * HD;     // 3072
static constexpr float SC2 = 0.08838834764831845f * 1.4426950408889634f; // HD^-.5 * log2(e)

__device__ __forceinline__ unsigned short f2bf(float f) {
  union { float f; unsigned u; } x; x.f = f;
  unsigned r = x.u + 0x7fffu + ((x.u >> 16) & 1u);   // RNE
  return (unsigned short)(r >> 16);
}
__device__ __forceinline__ float b2f(unsigned short h) {
  union { unsigned u; float f; } x; x.u = ((unsigned)h) << 16;
  return x.f;
}
__device__ __forceinline__ unsigned cvt_pk_bf16(float lo, float hi) {
  unsigned r;
  asm("v_cvt_pk_bf16_f32 %0, %1, %2" : "=v"(r) : "v"(lo), "v"(hi));
  return r;
}

// async global->LDS, 16B per lane. lds must be wave-uniform; HW adds lane*16.
__device__ __forceinline__ void gload_lds16(const void* g, void* lds) {
  auto gp = reinterpret_cast<const __attribute__((address_space(1))) unsigned int*>(
      reinterpret_cast<uintptr_t>(g));
  auto lp = reinterpret_cast<__attribute__((address_space(3))) unsigned int*>(
      static_cast<uint32_t>(reinterpret_cast<uintptr_t>(lds)));
  __builtin_amdgcn_global_load_lds(gp, lp, 16, 0, 0);
}

// ---------------------------------------------------------------------------
__global__ __launch_bounds__(256) void cast_f32_bf16(
    const float* __restrict__ in, unsigned short* __restrict__ out, int n) {
  int i = (blockIdx.x * 256 + threadIdx.x) * 4;
  if (i < n) {
    float4 v = *(const float4*)(in + i);
    ushort4 o;
    o.x = f2bf(v.x); o.y = f2bf(v.y); o.z = f2bf(v.z); o.w = f2bf(v.w);
    *(ushort4*)(out + i) = o;
  }
}

__global__ __launch_bounds__(256) void concat_bias(
    const float* __restrict__ qb, const float* __restrict__ kb,
    const float* __restrict__ vb, float* __restrict__ ob) {
  int i = blockIdx.x * 256 + threadIdx.x;
  if (i < NH * HD) ob[i] = qb[i];
  else if (i < NH * HD + NKV * HD) ob[i] = kb[i - NH * HD];
  else if (i < NQKV) ob[i] = vb[i - NH * HD - NKV * HD];
}

// ---------------------------------------------------------------------------
// C[M][N] = A[M][K] * B[N][K]^T (+bias). 128x128 tile, BK=32, 4 waves (2x2),
// each wave 64x64 = 4x4 fragments of 16x16x32 bf16 MFMA. m97 structure.
__device__ __forceinline__ void store_out(unsigned short* p, size_t i, float v) { p[i] = f2bf(v); }
__device__ __forceinline__ void store_out(float* p, size_t i, float v) { p[i] = v; }

template <typename OutT, bool HAS_BIAS>
__global__ __launch_bounds__(256) void gemm_bt(
    const unsigned short* __restrict__ A, const unsigned short* __restrict__ Bm,
    const float* __restrict__ bias, OutT* __restrict__ C, int K, int N) {
  __shared__ unsigned short As[128 * 32];
  __shared__ unsigned short Bs[128 * 32];
  const int t = threadIdx.x;
  const int lane = t & 63;
  const int l16 = lane & 15, lg = lane >> 4;
  const int w = t >> 6;
  const int wm = (w >> 1) * 64, wn = (w & 1) * 64;
  const int tm = blockIdx.x * 128, tn = blockIdx.y * 128;

  f32x4 acc[4][4] = {};

  for (int k0 = 0; k0 < K; k0 += 32) {
#pragma unroll
    for (int i = 0; i < 2; ++i) {
      int c = i * 256 + t;
      const unsigned short* ga = A + (size_t)(tm + (c >> 2)) * K + k0 + (c & 3) * 8;
      const unsigned short* gb = Bm + (size_t)(tn + (c >> 2)) * K + k0 + (c & 3) * 8;
      gload_lds16(ga, (char*)As + (((c >> 6)) << 10));
      gload_lds16(gb, (char*)Bs + (((c >> 6)) << 10));
    }
    __syncthreads();
    bf16x8 af[4], bfr[4];
#pragma unroll
    for (int m = 0; m < 4; ++m)
      af[m] = *(const bf16x8*)(As + (wm + m * 16 + l16) * 32 + lg * 8);
#pragma unroll
    for (int n = 0; n < 4; ++n)
      bfr[n] = *(const bf16x8*)(Bs + (wn + n * 16 + l16) * 32 + lg * 8);
#pragma unroll
    for (int m = 0; m < 4; ++m)
#pragma unroll
      for (int n = 0; n < 4; ++n)
        acc[m][n] = __builtin_amdgcn_mfma_f32_16x16x32_bf16(af[m], bfr[n], acc[m][n], 0, 0, 0);
    __syncthreads();
  }

#pragma unroll
  for (int m = 0; m < 4; ++m)
#pragma unroll
    for (int n = 0; n < 4; ++n) {
      int col = tn + wn + n * 16 + l16;
      float bv = HAS_BIAS ? bias[col] : 0.0f;
#pragma unroll
      for (int r = 0; r < 4; ++r) {
        int row = tm + wm + m * 16 + lg * 4 + r;
        store_out(C, (size_t)row * N + col, acc[m][n][r] + bv);
      }
    }
}

// ---------------------------------------------------------------------------
// RoPE on Q,K + scatter into head-major layouts. Q additionally pre-scaled by
// SC2 = HD^-0.5 * log2(e) so attention scores come out in log2 domain.
// QKV [4096][3072] bf16 -> Qr [B][NH][S][HD], Kr [B][NKV][S][HD]
__global__ __launch_bounds__(256) void rope_kernel(
    const unsigned short* __restrict__ QKV, const float* __restrict__ cosp,
    const float* __restrict__ sinp, unsigned short* __restrict__ Qr,
    unsigned short* __restrict__ Kr) {
  int row = blockIdx.x;            // b*S + s
  int b = row >> 11, s = row & 2047;
  const float* cb = cosp + (size_t)row * HD;
  const float* sb = sinp + (size_t)row * HD;
  const unsigned short* src = QKV + (size_t)row * NQKV;
  for (int p = threadIdx.x; p < (NH + NKV) * 64; p += 256) {
    int hh = p >> 6, d = p & 63;
    float c = cb[d], sn = sb[d];
    if (hh < NH) {
      float x1 = b2f(src[hh * HD + d]);
      float x2 = b2f(src[hh * HD + d + 64]);
      size_t o = ((size_t)(b * NH + hh) * Ssz + s) * HD + d;
      Qr[o] = f2bf((x1 * c - x2 * sn) * SC2);
      Qr[o + 64] = f2bf((x2 * c + x1 * sn) * SC2);
    } else {
      int g = hh - NH;
      float x1 = b2f(src[NH * HD + g * HD + d]);
      float x2 = b2f(src[NH * HD + g * HD + d + 64]);
      size_t o = ((size_t)(b * NKV + g) * Ssz + s) * HD + d;
      Kr[o] = f2bf(x1 * c - x2 * sn);
      Kr[o + 64] = f2bf(x2 * c + x1 * sn);
    }
  }
}

// V [b][s][g*HD+d] (cols 2560.. of QKV) -> Vt [B][NKV][HD][S]
__global__ __launch_bounds__(256) void vtrans_kernel(
    const unsigned short* __restrict__ QKV, unsigned short* __restrict__ Vt) {
  __shared__ unsigned short tile[32][33];
  int bg = blockIdx.x;             // b*NKV + g
  int s0 = blockIdx.y * 32, d0 = blockIdx.z * 32;
  int b = bg >> 2, g = bg & 3;
  int tx = threadIdx.x & 31, ty = threadIdx.x >> 5;  // 32 x 8
#pragma unroll
  for (int i = 0; i < 4; ++i) {
    int sl = ty + i * 8;
    tile[sl][tx] = QKV[(size_t)(b * Ssz + s0 + sl) * NQKV + (NH + NKV) * HD + g * HD + d0 + tx];
  }
  __syncthreads();
#pragma unroll
  for (int i = 0; i < 4; ++i) {
    int dl = ty + i * 8;
    Vt[((size_t)(b * NKV + g) * HD + d0 + dl) * Ssz + s0 + tx] = tile[tx][dl];
  }
}

// ---------------------------------------------------------------------------
// Flash causal GQA attention, v3.
// Grid: 1024 blocks, id = kvg + 8*(hr + 4*pr), pr in 0..31.
//   kvg (b*4+g) pins each KV group's blocks to one XCD (id%8).
// Block = 4 waves; waves 0,1 -> 32-row q-tile pr, waves 2,3 -> tile 63-pr.
// Per wave: 16 q-rows, KBLK=64. Swapped QK^T: sc = mfma(K, Q) puts q on
// lane&15, k on (lane>>4)*4+reg -> softmax reduce = in-lane tree + 2 shfl.
// Q pre-scaled by SC2 (log2-domain scores). Defer-max rescale (THR=8).
__global__ __launch_bounds__(256, 4) void attn_kernel(
    const unsigned short* __restrict__ Qr, const unsigned short* __restrict__ Kr,
    const unsigned short* __restrict__ Vt, unsigned short* __restrict__ O) {
  const int id = blockIdx.x;
  const int kvg = id & 7, j = id >> 3;
  const int hr = j & 3, pr = j >> 2;       // pr in 0..31
  const int b = kvg >> 2, g = kvg & 3;
  const int h = g * 4 + hr;
  const int wave = threadIdx.x >> 6;
  const int lane = threadIdx.x & 63;
  const int l16 = lane & 15, lg = lane >> 4;

  const int tile = (wave < 2) ? pr : (63 - pr);    // 32-row tile index
  const int qr0 = tile * 32 + (wave & 1) * 16;     // this wave's first q row

  const unsigned short* Qh = Qr + (size_t)(b * NH + h) * Ssz * HD;
  const unsigned short* Kh = Kr + (size_t)(b * NKV + g) * Ssz * HD;
  const unsigned short* Vh = Vt + (size_t)(b * NKV + g) * HD * Ssz;

  __shared__ unsigned short Plds[4][16][72];   // [wave][q-row][k], pad 72
  unsigned short(*pw)[72] = Plds[wave];

  // Q fragment (B operand of swapped MFMA): rows qr0..qr0+15
  bf16x8 aq[4];
#pragma unroll
  for (int c = 0; c < 4; ++c)
    aq[c] = *(const bf16x8*)(Qh + (size_t)(qr0 + l16) * HD + c * 32 + lg * 8);

  f32x4 acco[8] = {};
  float m_l = -INFINITY, s_l = 0.0f;   // per-lane: q = qr0 + l16 (replicated over lg)

  const int kend = qr0 + 16;           // exclusive causal bound for this wave

  auto kstep = [&](int k0, bool masked) {
    // ---- QK^T swapped: sc[kt] = K-tile x Q => C[k][q], q = l16
    f32x4 sc[4] = {};
#pragma unroll
    for (int kt = 0; kt < 4; ++kt) {
#pragma unroll
      for (int c = 0; c < 4; ++c) {
        bf16x8 bk = *(const bf16x8*)(Kh + (size_t)(k0 + kt * 16 + l16) * HD + c * 32 + lg * 8);
        sc[kt] = __builtin_amdgcn_mfma_f32_16x16x32_bf16(bk, aq[c], sc[kt], 0, 0, 0);
      }
    }
    // ---- prefetch V fragments (independent -> latency hides under softmax)
    bf16x8 bv[16];
#pragma unroll
    for (int kc = 0; kc < 2; ++kc)
#pragma unroll
      for (int dt = 0; dt < 8; ++dt)
        bv[kc * 8 + dt] =
            *(const bf16x8*)(Vh + (size_t)(dt * 16 + l16) * Ssz + k0 + kc * 32 + lg * 8);

    // ---- causal mask (tail iteration only). k = k0 + kt*16 + lg*4 + r, q = qr0+l16
    if (masked) {
      int qrow = qr0 + l16;
#pragma unroll
      for (int kt = 0; kt < 4; ++kt)
#pragma unroll
        for (int r = 0; r < 4; ++r)
          if (k0 + kt * 16 + lg * 4 + r > qrow) sc[kt][r] = -1e30f;
    }
    // ---- in-lane max over 16 values + 2-step cross-lg reduce
    float pm01 = fmaxf(fmaxf(sc[0][0], sc[0][1]), fmaxf(sc[0][2], sc[0][3]));
    float pm23 = fmaxf(fmaxf(sc[1][0], sc[1][1]), fmaxf(sc[1][2], sc[1][3]));
    float pm45 = fmaxf(fmaxf(sc[2][0], sc[2][1]), fmaxf(sc[2][2], sc[2][3]));
    float pm67 = fmaxf(fmaxf(sc[3][0], sc[3][1]), fmaxf(sc[3][2], sc[3][3]));
    float pmax = fmaxf(fmaxf(pm01, pm23), fmaxf(pm45, pm67));
    pmax = fmaxf(pmax, __shfl_xor(pmax, 16));
    pmax = fmaxf(pmax, __shfl_xor(pmax, 32));
    // ---- defer-max: only rescale when the running max grew by > 8 (log2)
    if (__any(pmax > m_l + 8.0f)) {
      float mnew = fmaxf(m_l, pmax);
      float f = exp2f(m_l - mnew);
      m_l = mnew;
      s_l *= f;
      float fr[4];
#pragma unroll
      for (int r = 0; r < 4; ++r) fr[r] = __shfl(f, lg * 4 + r);
#pragma unroll
      for (int dt = 0; dt < 8; ++dt)
#pragma unroll
        for (int r = 0; r < 4; ++r) acco[dt][r] *= fr[r];
    }
    // ---- exp2 in place + in-lane sum + 2-step cross-lg reduce
#pragma unroll
    for (int kt = 0; kt < 4; ++kt)
#pragma unroll
      for (int r = 0; r < 4; ++r) sc[kt][r] = exp2f(sc[kt][r] - m_l);
    float rs = ((sc[0][0] + sc[0][1]) + (sc[0][2] + sc[0][3])) +
               ((sc[1][0] + sc[1][1]) + (sc[1][2] + sc[1][3])) +
               ((sc[2][0] + sc[2][1]) + (sc[2][2] + sc[2][3])) +
               ((sc[3][0] + sc[3][1]) + (sc[3][2] + sc[3][3]));
    rs += __shfl_xor(rs, 16);
    rs += __shfl_xor(rs, 32);
    s_l += rs;
    // ---- pack P -> LDS (row q = l16? no: row index is q for the A-fragment
    //      read; this lane writes its 16 k-values into row l16 = its q)
#pragma unroll
    for (int kt = 0; kt < 4; ++kt) {
      uint2 pk;
      pk.x = cvt_pk_bf16(sc[kt][0], sc[kt][1]);
      pk.y = cvt_pk_bf16(sc[kt][2], sc[kt][3]);
      *(uint2*)(&pw[l16][kt * 16 + lg * 4]) = pk;
    }
    asm volatile("s_waitcnt lgkmcnt(0)" ::: "memory");
    __builtin_amdgcn_sched_barrier(0);
    // ---- PV: A = P (row=q=l16, k contiguous), B = Vt fragments
#pragma unroll
    for (int kc = 0; kc < 2; ++kc) {
      bf16x8 ap = *(const bf16x8*)(&pw[l16][kc * 32 + lg * 8]);
#pragma unroll
      for (int dt = 0; dt < 8; ++dt)
        acco[dt] = __builtin_amdgcn_mfma_f32_16x16x32_bf16(ap, bv[kc * 8 + dt], acco[dt], 0, 0, 0);
    }
  };

  int k0 = 0;
  for (; k0 + 64 <= qr0; k0 += 64) kstep(k0, false);
  for (; k0 < kend; k0 += 64) kstep(k0, true);   // exactly one masked iter

  // ---- epilogue: O rows q = qr0 + lg*4 + r, cols d = dt*16 + l16
  float inv[4];
#pragma unroll
  for (int r = 0; r < 4; ++r) inv[r] = 1.0f / __shfl(s_l, lg * 4 + r);
#pragma unroll
  for (int dt = 0; dt < 8; ++dt)
#pragma unroll
    for (int r = 0; r < 4; ++r) {
      int q = qr0 + lg * 4 + r;
      O[(size_t)(b * Ssz + q) * (NH * HD) + h * HD + dt * 16 + l16] =
          f2bf(acco[dt][r] * inv[r]);
    }
}

// ---------------------------------------------------------------------------
extern "C" void kernel_launch(void* const* d_in, const int* in_sizes, int n_in,
                              void* d_out, int out_size, void* d_ws, size_t ws_size,
                              hipStream_t stream) {
  const float* hs   = (const float*)d_in[0];
  const float* cosp = (const float*)d_in[1];
  const float* sinp = (const float*)d_in[2];
  // d_in[3] attention_mask: pure causal, handled analytically
  const float* q_w = (const float*)d_in[4];
  const float* q_b = (const float*)d_in[5];
  const float* k_w = (const float*)d_in[6];
  const float* k_b = (const float*)d_in[7];
  const float* v_w = (const float*)d_in[8];
  const float* v_b = (const float*)d_in[9];
  const float* o_w = (const float*)d_in[10];
  float* out = (float*)d_out;

  char* p = (char*)d_ws;
  unsigned short* Xb   = (unsigned short*)p; p += (size_t)Mrows * Hsz * 2;
  unsigned short* Wqkv = (unsigned short*)p; p += (size_t)NQKV * Hsz * 2;
  unsigned short* Wo   = (unsigned short*)p; p += (size_t)Hsz * Hsz * 2;
  unsigned short* QKV  = (unsigned short*)p; p += (size_t)Mrows * NQKV * 2;
  unsigned short* Qr   = (unsigned short*)p; p += (size_t)Bsz * NH * Ssz * HD * 2;
  unsigned short* Kr   = (unsigned short*)p; p += (size_t)Bsz * NKV * Ssz * HD * 2;
  unsigned short* Vt   = (unsigned short*)p; p += (size_t)Bsz * NKV * HD * Ssz * 2;
  unsigned short* Obuf = (unsigned short*)p; p += (size_t)Mrows * Hsz * 2;
  float* biasQKV = (float*)p; p += (size_t)NQKV * 4;

  // casts
  cast_f32_bf16<<<Mrows * Hsz / 1024, 256, 0, stream>>>(hs, Xb, Mrows * Hsz);
  cast_f32_bf16<<<NH * HD * Hsz / 1024, 256, 0, stream>>>(q_w, Wqkv, NH * HD * Hsz);
  cast_f32_bf16<<<NKV * HD * Hsz / 1024, 256, 0, stream>>>(
      k_w, Wqkv + (size_t)NH * HD * Hsz, NKV * HD * Hsz);
  cast_f32_bf16<<<NKV * HD * Hsz / 1024, 256, 0, stream>>>(
      v_w, Wqkv + (size_t)(NH + NKV) * HD * Hsz, NKV * HD * Hsz);
  cast_f32_bf16<<<Hsz * Hsz / 1024, 256, 0, stream>>>(o_w, Wo, Hsz * Hsz);
  concat_bias<<<(NQKV + 255) / 256, 256, 0, stream>>>(q_b, k_b, v_b, biasQKV);

  // QKV projection
  gemm_bt<unsigned short, true><<<dim3(Mrows / 128, NQKV / 128), 256, 0, stream>>>(
      Xb, Wqkv, biasQKV, QKV, Hsz, NQKV);

  // RoPE + reorder + V transpose
  rope_kernel<<<Mrows, 256, 0, stream>>>(QKV, cosp, sinp, Qr, Kr);
  vtrans_kernel<<<dim3(Bsz * NKV, Ssz / 32, HD / 32), 256, 0, stream>>>(QKV, Vt);

  // attention: 1024 blocks, kv-group pinned to XCD via id%8
  attn_kernel<<<1024, 256, 0, stream>>>(Qr, Kr, Vt, Obuf);

  // output projection -> f32
  gemm_bt<float, false><<<dim3(Mrows / 128, Hsz / 128), 256, 0, stream>>>(
      Obuf, Wo, nullptr, out, Hsz, Hsz);
}

// Round 4
// 401.321 us; speedup vs baseline: 1.2020x; 1.2020x over previous
//
#include <hip/hip_runtime.h>
#include <cstdint>

// ---------------------------------------------------------------------------
// Qwen2 attention block, MI355X/gfx950. Round 3: v4 attention —
// v3 structure (swapped QK^T, base-2 softmax, defer-max, tail-split, XCD pin,
// 1024 balanced blocks) with the register-spill fixed: no VGPR clamp, no
// bv[16] prefetch (V read inline, latency hidden by 4 waves/SIMD TLP).
// ---------------------------------------------------------------------------

typedef short bf16x8 __attribute__((ext_vector_type(8)));
typedef float f32x4 __attribute__((ext_vector_type(4)));

static constexpr int Bsz = 2, Ssz = 2048, Hsz = 2048;
static constexpr int NH = 16, NKV = 4, HD = 128;
static constexpr int Mrows = Bsz * Ssz;              // 4096
static constexpr int NQKV = (NH + 2 * NKV) * HD;     // 3072
static constexpr float SC2 = 0.08838834764831845f * 1.4426950408889634f; // HD^-.5 * log2(e)

__device__ __forceinline__ unsigned short f2bf(float f) {
  union { float f; unsigned u; } x; x.f = f;
  unsigned r = x.u + 0x7fffu + ((x.u >> 16) & 1u);   // RNE
  return (unsigned short)(r >> 16);
}
__device__ __forceinline__ float b2f(unsigned short h) {
  union { unsigned u; float f; } x; x.u = ((unsigned)h) << 16;
  return x.f;
}
__device__ __forceinline__ unsigned cvt_pk_bf16(float lo, float hi) {
  unsigned r;
  asm("v_cvt_pk_bf16_f32 %0, %1, %2" : "=v"(r) : "v"(lo), "v"(hi));
  return r;
}

// async global->LDS, 16B per lane. lds must be wave-uniform; HW adds lane*16.
__device__ __forceinline__ void gload_lds16(const void* g, void* lds) {
  auto gp = reinterpret_cast<const __attribute__((address_space(1))) unsigned int*>(
      reinterpret_cast<uintptr_t>(g));
  auto lp = reinterpret_cast<__attribute__((address_space(3))) unsigned int*>(
      static_cast<uint32_t>(reinterpret_cast<uintptr_t>(lds)));
  __builtin_amdgcn_global_load_lds(gp, lp, 16, 0, 0);
}

// ---------------------------------------------------------------------------
__global__ __launch_bounds__(256) void cast_f32_bf16(
    const float* __restrict__ in, unsigned short* __restrict__ out, int n) {
  int i = (blockIdx.x * 256 + threadIdx.x) * 4;
  if (i < n) {
    float4 v = *(const float4*)(in + i);
    ushort4 o;
    o.x = f2bf(v.x); o.y = f2bf(v.y); o.z = f2bf(v.z); o.w = f2bf(v.w);
    *(ushort4*)(out + i) = o;
  }
}

__global__ __launch_bounds__(256) void concat_bias(
    const float* __restrict__ qb, const float* __restrict__ kb,
    const float* __restrict__ vb, float* __restrict__ ob) {
  int i = blockIdx.x * 256 + threadIdx.x;
  if (i < NH * HD) ob[i] = qb[i];
  else if (i < NH * HD + NKV * HD) ob[i] = kb[i - NH * HD];
  else if (i < NQKV) ob[i] = vb[i - NH * HD - NKV * HD];
}

// ---------------------------------------------------------------------------
// C[M][N] = A[M][K] * B[N][K]^T (+bias). 128x128 tile, BK=32, 4 waves (2x2),
// each wave 64x64 = 4x4 fragments of 16x16x32 bf16 MFMA. m97 structure.
__device__ __forceinline__ void store_out(unsigned short* p, size_t i, float v) { p[i] = f2bf(v); }
__device__ __forceinline__ void store_out(float* p, size_t i, float v) { p[i] = v; }

template <typename OutT, bool HAS_BIAS>
__global__ __launch_bounds__(256) void gemm_bt(
    const unsigned short* __restrict__ A, const unsigned short* __restrict__ Bm,
    const float* __restrict__ bias, OutT* __restrict__ C, int K, int N) {
  __shared__ unsigned short As[128 * 32];
  __shared__ unsigned short Bs[128 * 32];
  const int t = threadIdx.x;
  const int lane = t & 63;
  const int l16 = lane & 15, lg = lane >> 4;
  const int w = t >> 6;
  const int wm = (w >> 1) * 64, wn = (w & 1) * 64;
  const int tm = blockIdx.x * 128, tn = blockIdx.y * 128;

  f32x4 acc[4][4] = {};

  for (int k0 = 0; k0 < K; k0 += 32) {
#pragma unroll
    for (int i = 0; i < 2; ++i) {
      int c = i * 256 + t;
      const unsigned short* ga = A + (size_t)(tm + (c >> 2)) * K + k0 + (c & 3) * 8;
      const unsigned short* gb = Bm + (size_t)(tn + (c >> 2)) * K + k0 + (c & 3) * 8;
      gload_lds16(ga, (char*)As + (((c >> 6)) << 10));
      gload_lds16(gb, (char*)Bs + (((c >> 6)) << 10));
    }
    __syncthreads();
    bf16x8 af[4], bfr[4];
#pragma unroll
    for (int m = 0; m < 4; ++m)
      af[m] = *(const bf16x8*)(As + (wm + m * 16 + l16) * 32 + lg * 8);
#pragma unroll
    for (int n = 0; n < 4; ++n)
      bfr[n] = *(const bf16x8*)(Bs + (wn + n * 16 + l16) * 32 + lg * 8);
#pragma unroll
    for (int m = 0; m < 4; ++m)
#pragma unroll
      for (int n = 0; n < 4; ++n)
        acc[m][n] = __builtin_amdgcn_mfma_f32_16x16x32_bf16(af[m], bfr[n], acc[m][n], 0, 0, 0);
    __syncthreads();
  }

#pragma unroll
  for (int m = 0; m < 4; ++m)
#pragma unroll
    for (int n = 0; n < 4; ++n) {
      int col = tn + wn + n * 16 + l16;
      float bv = HAS_BIAS ? bias[col] : 0.0f;
#pragma unroll
      for (int r = 0; r < 4; ++r) {
        int row = tm + wm + m * 16 + lg * 4 + r;
        store_out(C, (size_t)row * N + col, acc[m][n][r] + bv);
      }
    }
}

// ---------------------------------------------------------------------------
// RoPE on Q,K + scatter into head-major layouts. Q additionally pre-scaled by
// SC2 = HD^-0.5 * log2(e) so attention scores come out in log2 domain.
// QKV [4096][3072] bf16 -> Qr [B][NH][S][HD], Kr [B][NKV][S][HD]
__global__ __launch_bounds__(256) void rope_kernel(
    const unsigned short* __restrict__ QKV, const float* __restrict__ cosp,
    const float* __restrict__ sinp, unsigned short* __restrict__ Qr,
    unsigned short* __restrict__ Kr) {
  int row = blockIdx.x;            // b*S + s
  int b = row >> 11, s = row & 2047;
  const float* cb = cosp + (size_t)row * HD;
  const float* sb = sinp + (size_t)row * HD;
  const unsigned short* src = QKV + (size_t)row * NQKV;
  for (int p = threadIdx.x; p < (NH + NKV) * 64; p += 256) {
    int hh = p >> 6, d = p & 63;
    float c = cb[d], sn = sb[d];
    if (hh < NH) {
      float x1 = b2f(src[hh * HD + d]);
      float x2 = b2f(src[hh * HD + d + 64]);
      size_t o = ((size_t)(b * NH + hh) * Ssz + s) * HD + d;
      Qr[o] = f2bf((x1 * c - x2 * sn) * SC2);
      Qr[o + 64] = f2bf((x2 * c + x1 * sn) * SC2);
    } else {
      int g = hh - NH;
      float x1 = b2f(src[NH * HD + g * HD + d]);
      float x2 = b2f(src[NH * HD + g * HD + d + 64]);
      size_t o = ((size_t)(b * NKV + g) * Ssz + s) * HD + d;
      Kr[o] = f2bf(x1 * c - x2 * sn);
      Kr[o + 64] = f2bf(x2 * c + x1 * sn);
    }
  }
}

// V [b][s][g*HD+d] (cols 2560.. of QKV) -> Vt [B][NKV][HD][S]
__global__ __launch_bounds__(256) void vtrans_kernel(
    const unsigned short* __restrict__ QKV, unsigned short* __restrict__ Vt) {
  __shared__ unsigned short tile[32][33];
  int bg = blockIdx.x;             // b*NKV + g
  int s0 = blockIdx.y * 32, d0 = blockIdx.z * 32;
  int b = bg >> 2, g = bg & 3;
  int tx = threadIdx.x & 31, ty = threadIdx.x >> 5;  // 32 x 8
#pragma unroll
  for (int i = 0; i < 4; ++i) {
    int sl = ty + i * 8;
    tile[sl][tx] = QKV[(size_t)(b * Ssz + s0 + sl) * NQKV + (NH + NKV) * HD + g * HD + d0 + tx];
  }
  __syncthreads();
#pragma unroll
  for (int i = 0; i < 4; ++i) {
    int dl = ty + i * 8;
    Vt[((size_t)(b * NKV + g) * HD + d0 + dl) * Ssz + s0 + tx] = tile[tx][dl];
  }
}

// ---------------------------------------------------------------------------
// Flash causal GQA attention, v4 (= v3 minus register spill).
// Grid: 1024 blocks, id = kvg + 8*(hr + 4*pr), pr in 0..31.
//   kvg (b*4+g) pins each KV group's blocks to one XCD (id%8).
// Block = 4 waves; waves 0,1 -> 32-row q-tile pr, waves 2,3 -> tile 63-pr.
// Swapped QK^T (q lane-local), base-2 softmax (Q pre-scaled by SC2),
// defer-max rescale (THR=8), single masked tail iter, cvt_pk P pack.
// V read inline during PV: latency hidden by TLP (target 4 waves/SIMD).
__global__ __launch_bounds__(256) void attn_kernel(
    const unsigned short* __restrict__ Qr, const unsigned short* __restrict__ Kr,
    const unsigned short* __restrict__ Vt, unsigned short* __restrict__ O) {
  const int id = blockIdx.x;
  const int kvg = id & 7, j = id >> 3;
  const int hr = j & 3, pr = j >> 2;       // pr in 0..31
  const int b = kvg >> 2, g = kvg & 3;
  const int h = g * 4 + hr;
  const int wave = threadIdx.x >> 6;
  const int lane = threadIdx.x & 63;
  const int l16 = lane & 15, lg = lane >> 4;

  const int tile = (wave < 2) ? pr : (63 - pr);    // 32-row tile index
  const int qr0 = tile * 32 + (wave & 1) * 16;     // this wave's first q row

  const unsigned short* Qh = Qr + (size_t)(b * NH + h) * Ssz * HD;
  const unsigned short* Kh = Kr + (size_t)(b * NKV + g) * Ssz * HD;
  const unsigned short* Vh = Vt + (size_t)(b * NKV + g) * HD * Ssz;

  __shared__ unsigned short Plds[4][16][72];   // [wave][q-row][k], pad 72
  unsigned short(*pw)[72] = Plds[wave];

  // Q fragment (B operand of swapped MFMA): rows qr0..qr0+15
  bf16x8 aq[4];
#pragma unroll
  for (int c = 0; c < 4; ++c)
    aq[c] = *(const bf16x8*)(Qh + (size_t)(qr0 + l16) * HD + c * 32 + lg * 8);

  f32x4 acco[8] = {};
  float m_l = -INFINITY, s_l = 0.0f;   // per-lane: q = qr0 + l16 (replicated over lg)

  const int kend = qr0 + 16;           // exclusive causal bound for this wave

  auto kstep = [&](int k0, bool masked) {
    // ---- QK^T swapped: sc[kt] = K-tile x Q => C[k][q], q = l16
    f32x4 sc[4] = {};
#pragma unroll
    for (int kt = 0; kt < 4; ++kt) {
#pragma unroll
      for (int c = 0; c < 4; ++c) {
        bf16x8 bk = *(const bf16x8*)(Kh + (size_t)(k0 + kt * 16 + l16) * HD + c * 32 + lg * 8);
        sc[kt] = __builtin_amdgcn_mfma_f32_16x16x32_bf16(bk, aq[c], sc[kt], 0, 0, 0);
      }
    }
    // ---- causal mask (tail iteration only). k = k0 + kt*16 + lg*4 + r, q = qr0+l16
    if (masked) {
      int qrow = qr0 + l16;
#pragma unroll
      for (int kt = 0; kt < 4; ++kt)
#pragma unroll
        for (int r = 0; r < 4; ++r)
          if (k0 + kt * 16 + lg * 4 + r > qrow) sc[kt][r] = -1e30f;
    }
    // ---- in-lane max over 16 values + 2-step cross-lg reduce
    float pm01 = fmaxf(fmaxf(sc[0][0], sc[0][1]), fmaxf(sc[0][2], sc[0][3]));
    float pm23 = fmaxf(fmaxf(sc[1][0], sc[1][1]), fmaxf(sc[1][2], sc[1][3]));
    float pm45 = fmaxf(fmaxf(sc[2][0], sc[2][1]), fmaxf(sc[2][2], sc[2][3]));
    float pm67 = fmaxf(fmaxf(sc[3][0], sc[3][1]), fmaxf(sc[3][2], sc[3][3]));
    float pmax = fmaxf(fmaxf(pm01, pm23), fmaxf(pm45, pm67));
    pmax = fmaxf(pmax, __shfl_xor(pmax, 16));
    pmax = fmaxf(pmax, __shfl_xor(pmax, 32));
    // ---- defer-max: only rescale when the running max grew by > 8 (log2)
    if (__any(pmax > m_l + 8.0f)) {
      float mnew = fmaxf(m_l, pmax);
      float f = exp2f(m_l - mnew);
      m_l = mnew;
      s_l *= f;
      float fr[4];
#pragma unroll
      for (int r = 0; r < 4; ++r) fr[r] = __shfl(f, lg * 4 + r);
#pragma unroll
      for (int dt = 0; dt < 8; ++dt)
#pragma unroll
        for (int r = 0; r < 4; ++r) acco[dt][r] *= fr[r];
    }
    // ---- exp2 in place + in-lane sum + 2-step cross-lg reduce
#pragma unroll
    for (int kt = 0; kt < 4; ++kt)
#pragma unroll
      for (int r = 0; r < 4; ++r) sc[kt][r] = exp2f(sc[kt][r] - m_l);
    float rs = ((sc[0][0] + sc[0][1]) + (sc[0][2] + sc[0][3])) +
               ((sc[1][0] + sc[1][1]) + (sc[1][2] + sc[1][3])) +
               ((sc[2][0] + sc[2][1]) + (sc[2][2] + sc[2][3])) +
               ((sc[3][0] + sc[3][1]) + (sc[3][2] + sc[3][3]));
    rs += __shfl_xor(rs, 16);
    rs += __shfl_xor(rs, 32);
    s_l += rs;
    // ---- pack P -> LDS: this lane writes its 16 k-values into row l16 (its q)
#pragma unroll
    for (int kt = 0; kt < 4; ++kt) {
      uint2 pk;
      pk.x = cvt_pk_bf16(sc[kt][0], sc[kt][1]);
      pk.y = cvt_pk_bf16(sc[kt][2], sc[kt][3]);
      *(uint2*)(&pw[l16][kt * 16 + lg * 4]) = pk;
    }
    asm volatile("s_waitcnt lgkmcnt(0)" ::: "memory");
    __builtin_amdgcn_sched_barrier(0);
    // ---- PV: A = P (row=q=l16, k contiguous), B = Vt fragments read inline
#pragma unroll
    for (int kc = 0; kc < 2; ++kc) {
      bf16x8 ap = *(const bf16x8*)(&pw[l16][kc * 32 + lg * 8]);
#pragma unroll
      for (int dt = 0; dt < 8; ++dt) {
        bf16x8 bv = *(const bf16x8*)(Vh + (size_t)(dt * 16 + l16) * Ssz + k0 + kc * 32 + lg * 8);
        acco[dt] = __builtin_amdgcn_mfma_f32_16x16x32_bf16(ap, bv, acco[dt], 0, 0, 0);
      }
    }
  };

  int k0 = 0;
  for (; k0 + 64 <= qr0; k0 += 64) kstep(k0, false);
  for (; k0 < kend; k0 += 64) kstep(k0, true);   // exactly one masked iter

  // ---- epilogue: O rows q = qr0 + lg*4 + r, cols d = dt*16 + l16
  float inv[4];
#pragma unroll
  for (int r = 0; r < 4; ++r) inv[r] = 1.0f / __shfl(s_l, lg * 4 + r);
#pragma unroll
  for (int dt = 0; dt < 8; ++dt)
#pragma unroll
    for (int r = 0; r < 4; ++r) {
      int q = qr0 + lg * 4 + r;
      O[(size_t)(b * Ssz + q) * (NH * HD) + h * HD + dt * 16 + l16] =
          f2bf(acco[dt][r] * inv[r]);
    }
}

// ---------------------------------------------------------------------------
extern "C" void kernel_launch(void* const* d_in, const int* in_sizes, int n_in,
                              void* d_out, int out_size, void* d_ws, size_t ws_size,
                              hipStream_t stream) {
  const float* hs   = (const float*)d_in[0];
  const float* cosp = (const float*)d_in[1];
  const float* sinp = (const float*)d_in[2];
  // d_in[3] attention_mask: pure causal, handled analytically
  const float* q_w = (const float*)d_in[4];
  const float* q_b = (const float*)d_in[5];
  const float* k_w = (const float*)d_in[6];
  const float* k_b = (const float*)d_in[7];
  const float* v_w = (const float*)d_in[8];
  const float* v_b = (const float*)d_in[9];
  const float* o_w = (const float*)d_in[10];
  float* out = (float*)d_out;

  char* p = (char*)d_ws;
  unsigned short* Xb   = (unsigned short*)p; p += (size_t)Mrows * Hsz * 2;
  unsigned short* Wqkv = (unsigned short*)p; p += (size_t)NQKV * Hsz * 2;
  unsigned short* Wo   = (unsigned short*)p; p += (size_t)Hsz * Hsz * 2;
  unsigned short* QKV  = (unsigned short*)p; p += (size_t)Mrows * NQKV * 2;
  unsigned short* Qr   = (unsigned short*)p; p += (size_t)Bsz * NH * Ssz * HD * 2;
  unsigned short* Kr   = (unsigned short*)p; p += (size_t)Bsz * NKV * Ssz * HD * 2;
  unsigned short* Vt   = (unsigned short*)p; p += (size_t)Bsz * NKV * HD * Ssz * 2;
  unsigned short* Obuf = (unsigned short*)p; p += (size_t)Mrows * Hsz * 2;
  float* biasQKV = (float*)p; p += (size_t)NQKV * 4;

  // casts
  cast_f32_bf16<<<Mrows * Hsz / 1024, 256, 0, stream>>>(hs, Xb, Mrows * Hsz);
  cast_f32_bf16<<<NH * HD * Hsz / 1024, 256, 0, stream>>>(q_w, Wqkv, NH * HD * Hsz);
  cast_f32_bf16<<<NKV * HD * Hsz / 1024, 256, 0, stream>>>(
      k_w, Wqkv + (size_t)NH * HD * Hsz, NKV * HD * Hsz);
  cast_f32_bf16<<<NKV * HD * Hsz / 1024, 256, 0, stream>>>(
      v_w, Wqkv + (size_t)(NH + NKV) * HD * Hsz, NKV * HD * Hsz);
  cast_f32_bf16<<<Hsz * Hsz / 1024, 256, 0, stream>>>(o_w, Wo, Hsz * Hsz);
  concat_bias<<<(NQKV + 255) / 256, 256, 0, stream>>>(q_b, k_b, v_b, biasQKV);

  // QKV projection
  gemm_bt<unsigned short, true><<<dim3(Mrows / 128, NQKV / 128), 256, 0, stream>>>(
      Xb, Wqkv, biasQKV, QKV, Hsz, NQKV);

  // RoPE + reorder + V transpose
  rope_kernel<<<Mrows, 256, 0, stream>>>(QKV, cosp, sinp, Qr, Kr);
  vtrans_kernel<<<dim3(Bsz * NKV, Ssz / 32, HD / 32), 256, 0, stream>>>(QKV, Vt);

  // attention: 1024 blocks, kv-group pinned to XCD via id%8
  attn_kernel<<<1024, 256, 0, stream>>>(Qr, Kr, Vt, Obuf);

  // output projection -> f32
  gemm_bt<float, false><<<dim3(Mrows / 128, Hsz / 128), 256, 0, stream>>>(
      Obuf, Wo, nullptr, out, Hsz, Hsz);
}

// Round 5
// 234.309 us; speedup vs baseline: 2.0587x; 1.7128x over previous
//
#include <hip/hip_runtime.h>
#include <cstdint>

// ---------------------------------------------------------------------------
// Qwen2 attention block, MI355X/gfx950. Round 4: v5 attention —
// block-cooperative K/V LDS staging (double-buffered, global_load_lds with
// pre-swizzled source, counted vmcnt, raw barriers), 64-row q-tile per block,
// sequential causal pair. Softmax machinery from v4 (swapped QK^T, base-2,
// defer-max, single masked tail step).
// ---------------------------------------------------------------------------

typedef short bf16x8 __attribute__((ext_vector_type(8)));
typedef float f32x4 __attribute__((ext_vector_type(4)));

static constexpr int Bsz = 2, Ssz = 2048, Hsz = 2048;
static constexpr int NH = 16, NKV = 4, HD = 128;
static constexpr int Mrows = Bsz * Ssz;              // 4096
static constexpr int NQKV = (NH + 2 * NKV) * HD;     // 3072
static constexpr float SC2 = 0.08838834764831845f * 1.4426950408889634f; // HD^-.5 * log2(e)

__device__ __forceinline__ unsigned short f2bf(float f) {
  union { float f; unsigned u; } x; x.f = f;
  unsigned r = x.u + 0x7fffu + ((x.u >> 16) & 1u);   // RNE
  return (unsigned short)(r >> 16);
}
__device__ __forceinline__ float b2f(unsigned short h) {
  union { unsigned u; float f; } x; x.u = ((unsigned)h) << 16;
  return x.f;
}
__device__ __forceinline__ unsigned cvt_pk_bf16(float lo, float hi) {
  unsigned r;
  asm("v_cvt_pk_bf16_f32 %0, %1, %2" : "=v"(r) : "v"(lo), "v"(hi));
  return r;
}

// async global->LDS, 16B per lane. lds dest must be wave-uniform; HW adds lane*16.
__device__ __forceinline__ void gload_lds16(const void* g, void* lds) {
  auto gp = reinterpret_cast<const __attribute__((address_space(1))) unsigned int*>(
      reinterpret_cast<uintptr_t>(g));
  auto lp = reinterpret_cast<__attribute__((address_space(3))) unsigned int*>(
      static_cast<uint32_t>(reinterpret_cast<uintptr_t>(lds)));
  __builtin_amdgcn_global_load_lds(gp, lp, 16, 0, 0);
}

// ---------------------------------------------------------------------------
__global__ __launch_bounds__(256) void cast_f32_bf16(
    const float* __restrict__ in, unsigned short* __restrict__ out, int n) {
  int i = (blockIdx.x * 256 + threadIdx.x) * 4;
  if (i < n) {
    float4 v = *(const float4*)(in + i);
    ushort4 o;
    o.x = f2bf(v.x); o.y = f2bf(v.y); o.z = f2bf(v.z); o.w = f2bf(v.w);
    *(ushort4*)(out + i) = o;
  }
}

__global__ __launch_bounds__(256) void concat_bias(
    const float* __restrict__ qb, const float* __restrict__ kb,
    const float* __restrict__ vb, float* __restrict__ ob) {
  int i = blockIdx.x * 256 + threadIdx.x;
  if (i < NH * HD) ob[i] = qb[i];
  else if (i < NH * HD + NKV * HD) ob[i] = kb[i - NH * HD];
  else if (i < NQKV) ob[i] = vb[i - NH * HD - NKV * HD];
}

// ---------------------------------------------------------------------------
// C[M][N] = A[M][K] * B[N][K]^T (+bias). 128x128 tile, BK=32, 4 waves (2x2),
// each wave 64x64 = 4x4 fragments of 16x16x32 bf16 MFMA. m97 structure.
__device__ __forceinline__ void store_out(unsigned short* p, size_t i, float v) { p[i] = f2bf(v); }
__device__ __forceinline__ void store_out(float* p, size_t i, float v) { p[i] = v; }

template <typename OutT, bool HAS_BIAS>
__global__ __launch_bounds__(256) void gemm_bt(
    const unsigned short* __restrict__ A, const unsigned short* __restrict__ Bm,
    const float* __restrict__ bias, OutT* __restrict__ C, int K, int N) {
  __shared__ unsigned short As[128 * 32];
  __shared__ unsigned short Bs[128 * 32];
  const int t = threadIdx.x;
  const int lane = t & 63;
  const int l16 = lane & 15, lg = lane >> 4;
  const int w = t >> 6;
  const int wm = (w >> 1) * 64, wn = (w & 1) * 64;
  const int tm = blockIdx.x * 128, tn = blockIdx.y * 128;

  f32x4 acc[4][4] = {};

  for (int k0 = 0; k0 < K; k0 += 32) {
#pragma unroll
    for (int i = 0; i < 2; ++i) {
      int c = i * 256 + t;
      const unsigned short* ga = A + (size_t)(tm + (c >> 2)) * K + k0 + (c & 3) * 8;
      const unsigned short* gb = Bm + (size_t)(tn + (c >> 2)) * K + k0 + (c & 3) * 8;
      gload_lds16(ga, (char*)As + (((c >> 6)) << 10));
      gload_lds16(gb, (char*)Bs + (((c >> 6)) << 10));
    }
    __syncthreads();
    bf16x8 af[4], bfr[4];
#pragma unroll
    for (int m = 0; m < 4; ++m)
      af[m] = *(const bf16x8*)(As + (wm + m * 16 + l16) * 32 + lg * 8);
#pragma unroll
    for (int n = 0; n < 4; ++n)
      bfr[n] = *(const bf16x8*)(Bs + (wn + n * 16 + l16) * 32 + lg * 8);
#pragma unroll
    for (int m = 0; m < 4; ++m)
#pragma unroll
      for (int n = 0; n < 4; ++n)
        acc[m][n] = __builtin_amdgcn_mfma_f32_16x16x32_bf16(af[m], bfr[n], acc[m][n], 0, 0, 0);
    __syncthreads();
  }

#pragma unroll
  for (int m = 0; m < 4; ++m)
#pragma unroll
    for (int n = 0; n < 4; ++n) {
      int col = tn + wn + n * 16 + l16;
      float bv = HAS_BIAS ? bias[col] : 0.0f;
#pragma unroll
      for (int r = 0; r < 4; ++r) {
        int row = tm + wm + m * 16 + lg * 4 + r;
        store_out(C, (size_t)row * N + col, acc[m][n][r] + bv);
      }
    }
}

// ---------------------------------------------------------------------------
// RoPE on Q,K + scatter into head-major layouts. Q additionally pre-scaled by
// SC2 = HD^-0.5 * log2(e) so attention scores come out in log2 domain.
// QKV [4096][3072] bf16 -> Qr [B][NH][S][HD], Kr [B][NKV][S][HD]
__global__ __launch_bounds__(256) void rope_kernel(
    const unsigned short* __restrict__ QKV, const float* __restrict__ cosp,
    const float* __restrict__ sinp, unsigned short* __restrict__ Qr,
    unsigned short* __restrict__ Kr) {
  int row = blockIdx.x;            // b*S + s
  int b = row >> 11, s = row & 2047;
  const float* cb = cosp + (size_t)row * HD;
  const float* sb = sinp + (size_t)row * HD;
  const unsigned short* src = QKV + (size_t)row * NQKV;
  for (int p = threadIdx.x; p < (NH + NKV) * 64; p += 256) {
    int hh = p >> 6, d = p & 63;
    float c = cb[d], sn = sb[d];
    if (hh < NH) {
      float x1 = b2f(src[hh * HD + d]);
      float x2 = b2f(src[hh * HD + d + 64]);
      size_t o = ((size_t)(b * NH + hh) * Ssz + s) * HD + d;
      Qr[o] = f2bf((x1 * c - x2 * sn) * SC2);
      Qr[o + 64] = f2bf((x2 * c + x1 * sn) * SC2);
    } else {
      int g = hh - NH;
      float x1 = b2f(src[NH * HD + g * HD + d]);
      float x2 = b2f(src[NH * HD + g * HD + d + 64]);
      size_t o = ((size_t)(b * NKV + g) * Ssz + s) * HD + d;
      Kr[o] = f2bf(x1 * c - x2 * sn);
      Kr[o + 64] = f2bf(x2 * c + x1 * sn);
    }
  }
}

// V [b][s][g*HD+d] (cols 2560.. of QKV) -> Vt [B][NKV][HD][S]
__global__ __launch_bounds__(256) void vtrans_kernel(
    const unsigned short* __restrict__ QKV, unsigned short* __restrict__ Vt) {
  __shared__ unsigned short tile[32][33];
  int bg = blockIdx.x;             // b*NKV + g
  int s0 = blockIdx.y * 32, d0 = blockIdx.z * 32;
  int b = bg >> 2, g = bg & 3;
  int tx = threadIdx.x & 31, ty = threadIdx.x >> 5;  // 32 x 8
#pragma unroll
  for (int i = 0; i < 4; ++i) {
    int sl = ty + i * 8;
    tile[sl][tx] = QKV[(size_t)(b * Ssz + s0 + sl) * NQKV + (NH + NKV) * HD + g * HD + d0 + tx];
  }
  __syncthreads();
#pragma unroll
  for (int i = 0; i < 4; ++i) {
    int dl = ty + i * 8;
    Vt[((size_t)(b * NKV + g) * HD + d0 + dl) * Ssz + s0 + tx] = tile[tx][dl];
  }
}

// ---------------------------------------------------------------------------
// Flash causal GQA attention, v5: block-cooperative staged K/V.
// Grid: 512 blocks, id = kvg + 8*(hr + 4*pr), pr in 0..15.
//   kvg (b*4+g) keeps one KV group's blocks on one XCD (id%8 heuristic).
// Block = 4 waves sharing one 64-row q-tile (wave w owns rows +w*16);
// sequential causal pair: tile pr then tile 31-pr => 33 uniform k-steps.
// Per k-step (KBLK=64): K-tile 64x128 + V-tile 128x64 staged in dbuf LDS via
// global_load_lds with pre-swizzled source (chunk ^= row&7); consumed with
// swizzled ds_read_b128 (8 lanes/bank-group = wave64 minimum). Counted
// vmcnt(8) keeps next tile in flight across raw s_barriers.
__global__ __launch_bounds__(256) void attn_kernel(
    const unsigned short* __restrict__ Qr, const unsigned short* __restrict__ Kr,
    const unsigned short* __restrict__ Vt, unsigned short* __restrict__ O) {
  const int id = blockIdx.x;
  const int kvg = id & 7, j = id >> 3;
  const int hr = j & 3, pr = j >> 2;       // pr in 0..15
  const int b = kvg >> 2, g = kvg & 3;
  const int h = g * 4 + hr;
  const int wave = threadIdx.x >> 6;
  const int lane = threadIdx.x & 63;
  const int l16 = lane & 15, lg = lane >> 4;
  const int swz = l16 & 7;

  const unsigned short* Qh = Qr + (size_t)(b * NH + h) * Ssz * HD;
  const unsigned short* Kh = Kr + (size_t)(b * NKV + g) * Ssz * HD;
  const unsigned short* Vh = Vt + (size_t)(b * NKV + g) * HD * Ssz;

  __shared__ unsigned short Ks[2][64 * 128];   // [buf][row k][chunk-swizzled 128 d]
  __shared__ unsigned short Vs[2][128 * 64];   // [buf][row d][chunk-swizzled 64 k]
  __shared__ unsigned short Plds[4][16][72];
  unsigned short(*pw)[72] = Plds[wave];

  // Staging source offsets (elements). LDS linear pos (inst i, lane):
  //   K: row = i*4 + (lane>>4), c16 = lane&15 -> fetch G[row][c16 ^ (row&7)]
  //   V: row = i*8 + (lane>>3), c8 = lane&7  -> fetch G[row][c8  ^ (row&7)]
  int koff[4], voff[4];
#pragma unroll
  for (int ii = 0; ii < 4; ++ii) {
    int ik = wave * 4 + ii;
    int kr = ik * 4 + (lane >> 4);
    koff[ii] = kr * HD + (((lane & 15) ^ (kr & 7)) * 8);
    int vr = ik * 8 + (lane >> 3);
    voff[ii] = vr * Ssz + (((lane & 7) ^ (vr & 7)) * 8);
  }

  auto stage = [&](int buf, int k0) {
#pragma unroll
    for (int ii = 0; ii < 4; ++ii) {
      gload_lds16(Kh + (size_t)koff[ii] + (size_t)k0 * HD,
                  (char*)&Ks[buf][0] + (wave * 4 + ii) * 1024);
      gload_lds16(Vh + (size_t)voff[ii] + k0,
                  (char*)&Vs[buf][0] + (wave * 4 + ii) * 1024);
    }
  };

#pragma unroll 1
  for (int t = 0; t < 2; ++t) {
    const int qt = (t == 0) ? pr : (31 - pr);      // 64-row tile index
    const int qr0 = qt * 64 + wave * 16;

    bf16x8 aq[4];
#pragma unroll
    for (int c = 0; c < 4; ++c)
      aq[c] = *(const bf16x8*)(Qh + (size_t)(qr0 + l16) * HD + c * 32 + lg * 8);

    f32x4 acco[8] = {};
    float m_l = -INFINITY, s_l = 0.0f;   // per-lane: q = qr0 + l16

    stage(0, 0);
    int cur = 0;
#pragma unroll 1
    for (int s = 0; s <= qt; ++s) {
      const int k0 = s * 64;
      const bool masked = (s == qt);
      if (s < qt) {
        stage(cur ^ 1, k0 + 64);
        asm volatile("s_waitcnt vmcnt(8)" ::: "memory");
      } else {
        asm volatile("s_waitcnt vmcnt(0)" ::: "memory");
      }
      __builtin_amdgcn_s_barrier();           // current buffer ready (all waves)
      __builtin_amdgcn_sched_barrier(0);

      // ---- QK^T swapped: sc[kt] = K-tile x Q => C[k][q], q = l16
      f32x4 sc[4] = {};
#pragma unroll
      for (int kt = 0; kt < 4; ++kt) {
        const int krow = kt * 16 + l16;
#pragma unroll
        for (int c = 0; c < 4; ++c) {
          bf16x8 bk = *(const bf16x8*)((const char*)&Ks[cur][0] + krow * 256 +
                                       (((c * 4 + lg) ^ swz) * 16));
          sc[kt] = __builtin_amdgcn_mfma_f32_16x16x32_bf16(bk, aq[c], sc[kt], 0, 0, 0);
        }
      }
      // ---- causal mask (tail step only)
      if (masked) {
        int qrow = qr0 + l16;
#pragma unroll
        for (int kt = 0; kt < 4; ++kt)
#pragma unroll
          for (int r = 0; r < 4; ++r)
            if (k0 + kt * 16 + lg * 4 + r > qrow) sc[kt][r] = -1e30f;
      }
      // ---- in-lane max + 2-step cross-lg reduce
      float pm01 = fmaxf(fmaxf(sc[0][0], sc[0][1]), fmaxf(sc[0][2], sc[0][3]));
      float pm23 = fmaxf(fmaxf(sc[1][0], sc[1][1]), fmaxf(sc[1][2], sc[1][3]));
      float pm45 = fmaxf(fmaxf(sc[2][0], sc[2][1]), fmaxf(sc[2][2], sc[2][3]));
      float pm67 = fmaxf(fmaxf(sc[3][0], sc[3][1]), fmaxf(sc[3][2], sc[3][3]));
      float pmax = fmaxf(fmaxf(pm01, pm23), fmaxf(pm45, pm67));
      pmax = fmaxf(pmax, __shfl_xor(pmax, 16));
      pmax = fmaxf(pmax, __shfl_xor(pmax, 32));
      // ---- defer-max rescale (THR = 8 in log2 domain)
      if (__any(pmax > m_l + 8.0f)) {
        float mnew = fmaxf(m_l, pmax);
        float f = exp2f(m_l - mnew);
        m_l = mnew;
        s_l *= f;
        float fr[4];
#pragma unroll
        for (int r = 0; r < 4; ++r) fr[r] = __shfl(f, lg * 4 + r);
#pragma unroll
        for (int dt = 0; dt < 8; ++dt)
#pragma unroll
          for (int r = 0; r < 4; ++r) acco[dt][r] *= fr[r];
      }
      // ---- exp2 + sum
#pragma unroll
      for (int kt = 0; kt < 4; ++kt)
#pragma unroll
        for (int r = 0; r < 4; ++r) sc[kt][r] = exp2f(sc[kt][r] - m_l);
      float rs = ((sc[0][0] + sc[0][1]) + (sc[0][2] + sc[0][3])) +
                 ((sc[1][0] + sc[1][1]) + (sc[1][2] + sc[1][3])) +
                 ((sc[2][0] + sc[2][1]) + (sc[2][2] + sc[2][3])) +
                 ((sc[3][0] + sc[3][1]) + (sc[3][2] + sc[3][3]));
      rs += __shfl_xor(rs, 16);
      rs += __shfl_xor(rs, 32);
      s_l += rs;
      // ---- pack P -> LDS (lane's 16 k-values into row l16 = its q)
#pragma unroll
      for (int kt = 0; kt < 4; ++kt) {
        uint2 pk;
        pk.x = cvt_pk_bf16(sc[kt][0], sc[kt][1]);
        pk.y = cvt_pk_bf16(sc[kt][2], sc[kt][3]);
        *(uint2*)(&pw[l16][kt * 16 + lg * 4]) = pk;
      }
      asm volatile("s_waitcnt lgkmcnt(0)" ::: "memory");
      __builtin_amdgcn_sched_barrier(0);
      // ---- PV: A = P (row=q=l16), B = staged V (swizzled ds_read)
#pragma unroll
      for (int kc = 0; kc < 2; ++kc) {
        bf16x8 ap = *(const bf16x8*)(&pw[l16][kc * 32 + lg * 8]);
#pragma unroll
        for (int dt = 0; dt < 8; ++dt) {
          const int vrow = dt * 16 + l16;
          bf16x8 bv = *(const bf16x8*)((const char*)&Vs[cur][0] + vrow * 128 +
                                       (((kc * 4 + lg) ^ swz) * 16));
          acco[dt] = __builtin_amdgcn_mfma_f32_16x16x32_bf16(ap, bv, acco[dt], 0, 0, 0);
        }
      }
      __builtin_amdgcn_sched_barrier(0);
      __builtin_amdgcn_s_barrier();           // all waves done reading buffer
      cur ^= 1;
    }

    // ---- epilogue: O rows q = qr0 + lg*4 + r, cols d = dt*16 + l16
    float inv[4];
#pragma unroll
    for (int r = 0; r < 4; ++r) inv[r] = 1.0f / __shfl(s_l, lg * 4 + r);
#pragma unroll
    for (int dt = 0; dt < 8; ++dt)
#pragma unroll
      for (int r = 0; r < 4; ++r) {
        int q = qr0 + lg * 4 + r;
        O[(size_t)(b * Ssz + q) * (NH * HD) + h * HD + dt * 16 + l16] =
            f2bf(acco[dt][r] * inv[r]);
      }
    asm volatile("s_waitcnt vmcnt(0)" ::: "memory");  // drain stores before t=1
  }
}

// ---------------------------------------------------------------------------
extern "C" void kernel_launch(void* const* d_in, const int* in_sizes, int n_in,
                              void* d_out, int out_size, void* d_ws, size_t ws_size,
                              hipStream_t stream) {
  const float* hs   = (const float*)d_in[0];
  const float* cosp = (const float*)d_in[1];
  const float* sinp = (const float*)d_in[2];
  // d_in[3] attention_mask: pure causal, handled analytically
  const float* q_w = (const float*)d_in[4];
  const float* q_b = (const float*)d_in[5];
  const float* k_w = (const float*)d_in[6];
  const float* k_b = (const float*)d_in[7];
  const float* v_w = (const float*)d_in[8];
  const float* v_b = (const float*)d_in[9];
  const float* o_w = (const float*)d_in[10];
  float* out = (float*)d_out;

  char* p = (char*)d_ws;
  unsigned short* Xb   = (unsigned short*)p; p += (size_t)Mrows * Hsz * 2;
  unsigned short* Wqkv = (unsigned short*)p; p += (size_t)NQKV * Hsz * 2;
  unsigned short* Wo   = (unsigned short*)p; p += (size_t)Hsz * Hsz * 2;
  unsigned short* QKV  = (unsigned short*)p; p += (size_t)Mrows * NQKV * 2;
  unsigned short* Qr   = (unsigned short*)p; p += (size_t)Bsz * NH * Ssz * HD * 2;
  unsigned short* Kr   = (unsigned short*)p; p += (size_t)Bsz * NKV * Ssz * HD * 2;
  unsigned short* Vt   = (unsigned short*)p; p += (size_t)Bsz * NKV * HD * Ssz * 2;
  unsigned short* Obuf = (unsigned short*)p; p += (size_t)Mrows * Hsz * 2;
  float* biasQKV = (float*)p; p += (size_t)NQKV * 4;

  // casts
  cast_f32_bf16<<<Mrows * Hsz / 1024, 256, 0, stream>>>(hs, Xb, Mrows * Hsz);
  cast_f32_bf16<<<NH * HD * Hsz / 1024, 256, 0, stream>>>(q_w, Wqkv, NH * HD * Hsz);
  cast_f32_bf16<<<NKV * HD * Hsz / 1024, 256, 0, stream>>>(
      k_w, Wqkv + (size_t)NH * HD * Hsz, NKV * HD * Hsz);
  cast_f32_bf16<<<NKV * HD * Hsz / 1024, 256, 0, stream>>>(
      v_w, Wqkv + (size_t)(NH + NKV) * HD * Hsz, NKV * HD * Hsz);
  cast_f32_bf16<<<Hsz * Hsz / 1024, 256, 0, stream>>>(o_w, Wo, Hsz * Hsz);
  concat_bias<<<(NQKV + 255) / 256, 256, 0, stream>>>(q_b, k_b, v_b, biasQKV);

  // QKV projection
  gemm_bt<unsigned short, true><<<dim3(Mrows / 128, NQKV / 128), 256, 0, stream>>>(
      Xb, Wqkv, biasQKV, QKV, Hsz, NQKV);

  // RoPE + reorder + V transpose
  rope_kernel<<<Mrows, 256, 0, stream>>>(QKV, cosp, sinp, Qr, Kr);
  vtrans_kernel<<<dim3(Bsz * NKV, Ssz / 32, HD / 32), 256, 0, stream>>>(QKV, Vt);

  // attention: 512 blocks (2/CU), kv-group pinned to XCD via id%8
  attn_kernel<<<512, 256, 0, stream>>>(Qr, Kr, Vt, Obuf);

  // output projection -> f32
  gemm_bt<float, false><<<dim3(Mrows / 128, Hsz / 128), 256, 0, stream>>>(
      Obuf, Wo, nullptr, out, Hsz, Hsz);
}